// Round 5
// baseline (45.763 us; speedup 1.0000x reference)
//
#include <hip/hip_runtime.h>
#include <hip/hip_bf16.h>
#include <math.h>

#define NUM_ITEMS 10000
#define EMBED_DIM 64
#define MAX_HIST 200
#define NPAD 208          // MAX_HIST padded to multiple of 16
#define BATCH 32
#define LEAKY 0.2f
#define W_USER 0.5f
#define LOG2E 1.4426950408889634f
#define ECLAMP 110.0f     // exp2 ceiling: Sh <= 208*2^110*2^6*4 ~ 2^126 < FLT_MAX

typedef short bf16x8 __attribute__((ext_vector_type(8)));
typedef float f32x4 __attribute__((ext_vector_type(4)));

__device__ __forceinline__ unsigned short f2bf(float f) {
    __hip_bfloat16 h = __float2bfloat16(f);
    return __builtin_bit_cast(unsigned short, h);
}

__device__ __forceinline__ float fexp2(float x) {
#if __has_builtin(__builtin_amdgcn_exp2f)
    return __builtin_amdgcn_exp2f(x);
#else
    return exp2f(x);
#endif
}

// ---------------- Kernel P (fused prep):
// blocks [0, NUM_ITEMS/4):      wti_bf = bf16(items@W), items_att_bf = bf16(items*log2e), bdot
// blocks [NUM_ITEMS/4, +BATCH): hist gather -> bf16 (NPAD rows), user softmax -> uh_bf[b][64]
__global__ __launch_bounds__(256) void prep_kernel(const int* __restrict__ ids,
                                                   const int* __restrict__ lens,
                                                   const float* __restrict__ items,
                                                   const float* __restrict__ user,
                                                   const float* __restrict__ W,
                                                   const float* __restrict__ bias,
                                                   unsigned short* __restrict__ items_att_bf,
                                                   unsigned short* __restrict__ wti_bf,
                                                   float* __restrict__ bdot,
                                                   unsigned short* __restrict__ hist_bf,
                                                   unsigned short* __restrict__ uh_bf) {
    const int tid = threadIdx.x;
    __shared__ float shW[EMBED_DIM * EMBED_DIM];  // 16 KB (wti part only)
    __shared__ float red[8];
    __shared__ float sh_usf[NPAD];
    __shared__ float sh_uh[4][EMBED_DIM];

    if (blockIdx.x < NUM_ITEMS / 4) {
        // ---- WtI part ----
        for (int idx = tid; idx < EMBED_DIM * EMBED_DIM; idx += 256) shW[idx] = W[idx];
        __syncthreads();

        const int i = blockIdx.x * 4 + (tid >> 6);
        const int g = tid & 63;
        const float* irow = items + i * EMBED_DIM;

        float acc = 0.f;
#pragma unroll
        for (int f = 0; f < EMBED_DIM; ++f) acc += irow[f] * shW[f * EMBED_DIM + g];

        wti_bf[i * EMBED_DIM + g] = f2bf(acc);
        // pre-scale attention operand by log2(e): leaky is positively homogeneous,
        // so exp2(log2e * leaky(s)) == exp(leaky(s)) exactly
        items_att_bf[i * EMBED_DIM + g] = f2bf(irow[g] * LOG2E);

        float bv = bias[g] * irow[g];
#pragma unroll
        for (int o = 32; o > 0; o >>= 1) bv += __shfl_xor(bv, o, 64);
        if (g == 0) bdot[i] = bv;
    } else {
        // ---- hist gather + user softmax + uh part ----
        const int b = blockIdx.x - NUM_ITEMS / 4;

        for (int idx = tid; idx < NPAD * 8; idx += 256) {
            const int n = idx >> 3, q = idx & 7;
            bf16x8 v = (bf16x8)0;
            if (n < MAX_HIST) {
                const int id = ids[b * MAX_HIST + n];
                const float4* p = (const float4*)(items + id * EMBED_DIM + q * 8);
                float4 v0 = p[0], v1 = p[1];
                v[0] = (short)f2bf(v0.x); v[1] = (short)f2bf(v0.y);
                v[2] = (short)f2bf(v0.z); v[3] = (short)f2bf(v0.w);
                v[4] = (short)f2bf(v1.x); v[5] = (short)f2bf(v1.y);
                v[6] = (short)f2bf(v1.z); v[7] = (short)f2bf(v1.w);
            }
            *(bf16x8*)(hist_bf + (size_t)(b * NPAD + n) * EMBED_DIM + q * 8) = v;
        }

        const int len = lens[b];
        float s = -INFINITY;
        if (tid < len) {
            const int id = ids[b * MAX_HIST + tid];
            const float* h = items + id * EMBED_DIM;
            float a0 = 0.f, a1 = 0.f;
#pragma unroll
            for (int f = 0; f < EMBED_DIM; f += 2) {
                a0 += user[f] * h[f];
                a1 += user[f + 1] * h[f + 1];
            }
            float a = a0 + a1;
            s = fmaxf(a, LEAKY * a);
        }
        float m = s;
#pragma unroll
        for (int o = 32; o > 0; o >>= 1) m = fmaxf(m, __shfl_xor(m, o, 64));
        if ((tid & 63) == 0) red[tid >> 6] = m;
        __syncthreads();
        m = fmaxf(fmaxf(red[0], red[1]), fmaxf(red[2], red[3]));

        float e = (tid < len) ? __expf(s - m) : 0.f;
        float t = e;
#pragma unroll
        for (int o = 32; o > 0; o >>= 1) t += __shfl_xor(t, o, 64);
        if ((tid & 63) == 0) red[4 + (tid >> 6)] = t;
        __syncthreads();
        const float sum = red[4] + red[5] + red[6] + red[7];

        if (tid < NPAD) sh_usf[tid] = (tid < len) ? (e / sum) : 0.f;
        __syncthreads();

        // uh[f] = sum_n us[n] * items[ids[n]][f]   (fp32 accumulate, bf16 store)
        const int f = tid & 63;
        const int part = tid >> 6;
        float uhp = 0.f;
        for (int n = part; n < len; n += 4)
            uhp += sh_usf[n] * items[(size_t)ids[b * MAX_HIST + n] * EMBED_DIM + f];
        sh_uh[part][f] = uhp;
        __syncthreads();
        if (tid < EMBED_DIM)
            uh_bf[b * EMBED_DIM + tid] =
                f2bf(sh_uh[0][tid] + sh_uh[1][tid] + sh_uh[2][tid] + sh_uh[3][tid]);
    }
}

// ---------------- Kernel C: MFMA main, len-adaptive, clamped fixed-scale softmax
__global__ __launch_bounds__(256) void main_kernel(const unsigned short* __restrict__ items_att_bf,
                                                   const unsigned short* __restrict__ wti_bf,
                                                   const float* __restrict__ bdot,
                                                   const unsigned short* __restrict__ hist_bf,
                                                   const unsigned short* __restrict__ uh_bf,
                                                   const int* __restrict__ lens,
                                                   float* __restrict__ out) {
    const int b = blockIdx.y;
    const int tid = threadIdx.x;
    const int lane = tid & 63;
    const int w = tid >> 6;

    __shared__ __align__(16) unsigned short sh_hist[NPAD * EMBED_DIM];  // 26.6 KB, swizzled

    const int len = lens[b];                 // block-uniform
    const int ntiles = (len + 15) >> 4;      // 1..13

    // stage only the rows we need (XOR-swizzle: row stride 128 B)
    const float4* src = (const float4*)(hist_bf + (size_t)b * NPAD * EMBED_DIM);
    const int nf4 = ntiles * 16 * 8;
    for (int c = tid; c < nf4; c += 256) {
        const int n = c >> 3, q = c & 7;
        float4 v = src[c];
        const int byte = (n * 128 + q * 16) ^ ((n & 7) << 4);
        *(float4*)((char*)sh_hist + byte) = v;
    }
    __syncthreads();

    const int i0 = blockIdx.x * 64 + w * 16;
    if (i0 >= NUM_ITEMS) return;

    const int c16 = lane & 15;   // item column within 16-group
    const int g = lane >> 4;     // k-chunk / n-subrow group
    const int i = i0 + c16;

    // B-fragments (col = lane&15, k = 32*kk + 8*g .. +7)
    bf16x8 itf0 = *(const bf16x8*)(items_att_bf + (size_t)i * 64 + g * 8);
    bf16x8 itf1 = *(const bf16x8*)(items_att_bf + (size_t)i * 64 + 32 + g * 8);
    bf16x8 wtf0 = *(const bf16x8*)(wti_bf + (size_t)i * 64 + g * 8);
    bf16x8 wtf1 = *(const bf16x8*)(wti_bf + (size_t)i * 64 + 32 + g * 8);

    // user-perspective term via broadcast-A MFMA: Su = uh[b] . wti[i]
    // (A rows all equal uh -> C[r,c] = Su[c] for every r)
    bf16x8 u0 = *(const bf16x8*)(uh_bf + b * 64 + g * 8);
    bf16x8 u1 = *(const bf16x8*)(uh_bf + b * 64 + 32 + g * 8);
    f32x4 suf = (f32x4)0.f;
    suf = __builtin_amdgcn_mfma_f32_16x16x32_bf16(u0, wtf0, suf, 0, 0, 0);
    suf = __builtin_amdgcn_mfma_f32_16x16x32_bf16(u1, wtf1, suf, 0, 0, 0);
    const float Su = suf[0];

    float Se = 0.f, Sh = 0.f;

#define TILE_BODY(T, MASKED)                                                              \
    {                                                                                     \
        const int n = (T) * 16 + c16;                                                     \
        const int base = n * 128, sw = (n & 7) << 4;                                      \
        bf16x8 a0 = *(const bf16x8*)((const char*)sh_hist + ((base + g * 16) ^ sw));      \
        bf16x8 a1 = *(const bf16x8*)((const char*)sh_hist + ((base + 64 + g * 16) ^ sw)); \
        f32x4 S = (f32x4)0.f, H = (f32x4)0.f;                                             \
        S = __builtin_amdgcn_mfma_f32_16x16x32_bf16(a0, itf0, S, 0, 0, 0);                \
        S = __builtin_amdgcn_mfma_f32_16x16x32_bf16(a1, itf1, S, 0, 0, 0);                \
        H = __builtin_amdgcn_mfma_f32_16x16x32_bf16(a0, wtf0, H, 0, 0, 0);                \
        H = __builtin_amdgcn_mfma_f32_16x16x32_bf16(a1, wtf1, H, 0, 0, 0);                \
        const int nb = (T) * 16 + g * 4;                                                  \
        float s0 = fmaxf(S[0], LEAKY * S[0]);                                             \
        float s1 = fmaxf(S[1], LEAKY * S[1]);                                             \
        float s2 = fmaxf(S[2], LEAKY * S[2]);                                             \
        float s3 = fmaxf(S[3], LEAKY * S[3]);                                             \
        if (MASKED) {                                                                     \
            s0 = (nb + 0 < len) ? s0 : -INFINITY;                                         \
            s1 = (nb + 1 < len) ? s1 : -INFINITY;                                         \
            s2 = (nb + 2 < len) ? s2 : -INFINITY;                                         \
            s3 = (nb + 3 < len) ? s3 : -INFINITY;                                         \
        }                                                                                 \
        const float e0 = fexp2(fminf(s0, ECLAMP)), e1 = fexp2(fminf(s1, ECLAMP));         \
        const float e2 = fexp2(fminf(s2, ECLAMP)), e3 = fexp2(fminf(s3, ECLAMP));         \
        Se += (e0 + e1) + (e2 + e3);                                                      \
        Sh = fmaf(e0, H[0], fmaf(e1, H[1], fmaf(e2, H[2], fmaf(e3, H[3], Sh))));          \
    }

    // full tiles (unmasked), then one masked final tile (len>=1 -> ntiles>=1)
    for (int t = 0; t < ntiles - 1; ++t) TILE_BODY(t, 0)
    TILE_BODY(ntiles - 1, 1)
#undef TILE_BODY

    // fixed-scale combine across the 4 n-groups; clamp bounds Sh ~ 2^126 < FLT_MAX
    Se += __shfl_xor(Se, 16, 64); Se += __shfl_xor(Se, 32, 64);
    Sh += __shfl_xor(Sh, 16, 64); Sh += __shfl_xor(Sh, 32, 64);

    if (g == 0)
        out[(size_t)b * NUM_ITEMS + i] =
            (1.0f - W_USER) * (Sh / Se) + W_USER * Su + bdot[i];
}

extern "C" void kernel_launch(void* const* d_in, const int* in_sizes, int n_in,
                              void* d_out, int out_size, void* d_ws, size_t ws_size,
                              hipStream_t stream) {
    const int* ids = (const int*)d_in[0];
    const int* lens = (const int*)d_in[1];
    const float* items = (const float*)d_in[2];
    const float* user = (const float*)d_in[3];
    const float* W = (const float*)d_in[4];
    const float* bias = (const float*)d_in[5];
    float* out = (float*)d_out;

    char* p = (char*)d_ws;
    unsigned short* items_att_bf = (unsigned short*)p; p += (size_t)NUM_ITEMS * EMBED_DIM * 2;
    unsigned short* wti_bf       = (unsigned short*)p; p += (size_t)NUM_ITEMS * EMBED_DIM * 2;
    float* bdot                  = (float*)p;          p += (size_t)NUM_ITEMS * 4;
    unsigned short* hist_bf      = (unsigned short*)p; p += (size_t)BATCH * NPAD * EMBED_DIM * 2;
    unsigned short* uh_bf        = (unsigned short*)p; p += (size_t)BATCH * EMBED_DIM * 2;

    prep_kernel<<<NUM_ITEMS / 4 + BATCH, 256, 0, stream>>>(ids, lens, items, user, W, bias,
                                                           items_att_bf, wti_bf, bdot,
                                                           hist_bf, uh_bf);

    dim3 grid((NUM_ITEMS + 63) / 64, BATCH);
    main_kernel<<<grid, 256, 0, stream>>>(items_att_bf, wti_bf, bdot, hist_bf, uh_bf, lens, out);
}